// Round 5
// baseline (163.924 us; speedup 1.0000x reference)
//
#include <hip/hip_runtime.h>

// Problem constants (fixed by the reference setup)
#define BB 2
#define NN 4096
#define EE 65536
#define MM 4
#define HH 256
#define CAP 32   // actual in-degree is exactly 16 per node; 32 gives safety margin
#define NPB 4    // nodes per block in the fused kernel (16.9 KB LDS -> 8 blocks/CU)

typedef float vf4 __attribute__((ext_vector_type(4)));
typedef int vi2 __attribute__((ext_vector_type(2)));

// ---------------------------------------------------------------------------
// Kernel 1: zero the per-node counters
// ---------------------------------------------------------------------------
__global__ void k_zero(int* __restrict__ p, int n) {
  const int i = blockIdx.x * blockDim.x + threadIdx.x;
  if (i < n) p[i] = 0;
}

// ---------------------------------------------------------------------------
// Kernel 2 (fused coeff+build): one 64-lane wave per edge.
//   coeff = edge_fts[b,e,:] . edge_W + edge_b   (float4/lane + shuffle reduce)
//   lane 0: slot = (b, tgt); p = atomicAdd(cnt); packed[slot*CAP+p] = {src, coeff}
// edge_fts (134 MB) and cfg are single-use per call -> NONTEMPORAL loads so they
// don't evict the reused working set (hint/node_fts) from L2/LLC.
// ---------------------------------------------------------------------------
__global__ __launch_bounds__(256) void k_coeff_build(const float* __restrict__ edge_fts,
                                                     const float* __restrict__ edge_W,
                                                     const float* __restrict__ edge_b,
                                                     const int* __restrict__ cfg,
                                                     int* __restrict__ cnt,
                                                     int2* __restrict__ packed) {
  const int gid = blockIdx.x * blockDim.x + threadIdx.x;
  const int widx = gid >> 6;   // flat edge index b*E+e
  const int lane = gid & 63;
  if (widx >= BB * EE) return;
  const vf4 ef = __builtin_nontemporal_load(
      reinterpret_cast<const vf4*>(edge_fts + (size_t)widx * HH + lane * 4));
  const float4 wv = *reinterpret_cast<const float4*>(edge_W + lane * 4);
  float s = ef.x * wv.x + ef.y * wv.y + ef.z * wv.z + ef.w * wv.w;
#pragma unroll
  for (int off = 32; off > 0; off >>= 1) s += __shfl_down(s, off);
  if (lane == 0) {
    const int b = widx >> 16;  // E = 65536
    const vi2 st = __builtin_nontemporal_load(
        reinterpret_cast<const vi2*>(cfg + (size_t)widx * 2));  // (src, tgt)
    const int slot = b * NN + st.y;
    const int p = atomicAdd(&cnt[slot], 1);
    if (p < CAP) {
      int2 v;
      v.x = st.x;                              // src node
      v.y = __float_as_int(s + edge_b[0]);     // coeff
      packed[(size_t)slot * CAP + p] = v;
    }
  }
}

__device__ __forceinline__ float4 fmax4(const float4& a, const float4& b) {
  return make_float4(fmaxf(a.x, b.x), fmaxf(a.y, b.y), fmaxf(a.z, b.z), fmaxf(a.w, b.w));
}

// ---------------------------------------------------------------------------
// Kernel 3 (fused): per block of 4 nodes:
//   stage 0: stage the block's 4x16 (src,coeff) pairs into LDS
//   stage 1: x[i,m,h] = node_fts + max_e coeff[e]*hint[src[e],m,h]  -> LDS (16KB)
//            fast path (deg==16): 16 INDEPENDENT float4 loads in flight, fmax tree
//   stage 2: out = x @ W + bias  (fp32 VALU GEMM, 16x256 @ 256x256)
//            thread t -> rows (t>>6)*4..+3, cols j0=(t&63)*4..+3 (float4 W/out)
//   out stores are NONTEMPORAL (single-use write, keep LLC for hint/node).
// ---------------------------------------------------------------------------
__global__ __launch_bounds__(256) void k_fused(const float* __restrict__ hint,
                                               const float* __restrict__ node_fts,
                                               const int* __restrict__ cnt,
                                               const int2* __restrict__ packed,
                                               const float* __restrict__ W,
                                               const float* __restrict__ bias,
                                               float* __restrict__ out) {
  __shared__ float xs[NPB * MM][HH];  // 16 KB
  __shared__ int ssrc[NPB][16];
  __shared__ float scf[NPB][16];
  __shared__ int sdeg[NPB];

  const int t = threadIdx.x;
  const int blk = blockIdx.x;
  const int b = blk / (NN / NPB);
  const int n0 = (blk % (NN / NPB)) * NPB;
  const int m = t >> 6;   // 0..3 (wave id)
  const int hq = t & 63;  // float4 index along H

  const float NEG_INF = __int_as_float(0xff800000);

  // ---- stage 0: stage (src,coeff) pairs ----
  if (t < NPB) sdeg[t] = cnt[b * NN + n0 + t];
  __syncthreads();
  if (t < NPB * 16) {
    const int i = t >> 4, k = t & 15;
    if (k < min(sdeg[i], CAP)) {
      const int2 v = packed[(size_t)(b * NN + n0 + i) * CAP + k];
      ssrc[i][k] = v.x;
      scf[i][k] = __int_as_float(v.y);
    }
  }
  __syncthreads();

  // per-thread base into hint for (b, m, hq)
  const float* hb = hint + (size_t)b * NN * MM * HH + m * HH + hq * 4;

  // ---- stage 1: gather + coeff-scale + max + add node_fts ----
#pragma unroll 1
  for (int i = 0; i < NPB; ++i) {
    const int deg = sdeg[i];
    float4 acc;
    if (deg == 16) {
      float4 hv[16];
#pragma unroll
      for (int k = 0; k < 16; ++k) {
        const int s = ssrc[i][k];
        hv[k] = *reinterpret_cast<const float4*>(hb + (size_t)s * (MM * HH));
      }
#pragma unroll
      for (int k = 0; k < 16; ++k) {
        const float c = scf[i][k];
        hv[k].x *= c; hv[k].y *= c; hv[k].z *= c; hv[k].w *= c;
      }
#pragma unroll
      for (int off = 8; off > 0; off >>= 1)
#pragma unroll
        for (int k = 0; k < 8; ++k)
          if (k < off) hv[k] = fmax4(hv[k], hv[k + off]);
      acc = hv[0];
    } else {
      // generic path (deg != 16): read packed list straight from global
      acc = make_float4(NEG_INF, NEG_INF, NEG_INF, NEG_INF);
      const int2* pl = packed + (size_t)(b * NN + n0 + i) * CAP;
      const int d = min(deg, CAP);
      for (int k = 0; k < d; ++k) {
        const int2 v = pl[k];
        const float c = __int_as_float(v.y);
        const float4 hv = *reinterpret_cast<const float4*>(hb + (size_t)v.x * (MM * HH));
        acc.x = fmaxf(acc.x, c * hv.x);
        acc.y = fmaxf(acc.y, c * hv.y);
        acc.z = fmaxf(acc.z, c * hv.z);
        acc.w = fmaxf(acc.w, c * hv.w);
      }
    }
    const float4 nf = *reinterpret_cast<const float4*>(
        node_fts + (((size_t)(b * NN + n0 + i) * MM + m) * HH) + hq * 4);
    float4 xv;
    xv.x = nf.x + acc.x;
    xv.y = nf.y + acc.y;
    xv.z = nf.z + acc.z;
    xv.w = nf.w + acc.w;
    *reinterpret_cast<float4*>(&xs[i * MM + m][hq * 4]) = xv;
  }
  __syncthreads();

  // ---- stage 2: [16 x 256] @ [256 x 256] fp32 GEMM ----
  const int j0 = (t & 63) * 4;  // 4 consecutive output columns
  const int rg = t >> 6;        // rows rg*4 .. rg*4+3

  float4 acc2[4];
#pragma unroll
  for (int r = 0; r < 4; ++r) acc2[r] = make_float4(0.f, 0.f, 0.f, 0.f);

  for (int hq2 = 0; hq2 < HH / 4; ++hq2) {
    float4 xv[4];
#pragma unroll
    for (int r = 0; r < 4; ++r)
      xv[r] = *reinterpret_cast<const float4*>(&xs[rg * 4 + r][hq2 * 4]);
#pragma unroll
    for (int hh = 0; hh < 4; ++hh) {
      const float4 wq = *reinterpret_cast<const float4*>(W + (size_t)(hq2 * 4 + hh) * HH + j0);
#pragma unroll
      for (int r = 0; r < 4; ++r) {
        const float xr = (hh == 0) ? xv[r].x : (hh == 1) ? xv[r].y : (hh == 2) ? xv[r].z : xv[r].w;
        acc2[r].x = fmaf(xr, wq.x, acc2[r].x);
        acc2[r].y = fmaf(xr, wq.y, acc2[r].y);
        acc2[r].z = fmaf(xr, wq.z, acc2[r].z);
        acc2[r].w = fmaf(xr, wq.w, acc2[r].w);
      }
    }
  }

  // ---- write out (+bias), nontemporal float4 per row ----
  const float4 bq = *reinterpret_cast<const float4*>(bias + j0);
#pragma unroll
  for (int r = 0; r < 4; ++r) {
    const int row = rg * 4 + r;
    const int i = row >> 2;
    const int m2 = row & 3;
    vf4 o;
    o.x = acc2[r].x + bq.x;
    o.y = acc2[r].y + bq.y;
    o.z = acc2[r].z + bq.z;
    o.w = acc2[r].w + bq.w;
    __builtin_nontemporal_store(
        o, reinterpret_cast<vf4*>(out + (((size_t)(b * NN + n0 + i) * MM + m2) * HH) + j0));
  }
}

// ---------------------------------------------------------------------------
extern "C" void kernel_launch(void* const* d_in, const int* in_sizes, int n_in,
                              void* d_out, int out_size, void* d_ws, size_t ws_size,
                              hipStream_t stream) {
  const int* cfg = (const int*)d_in[0];          // [B,E,2]
  const float* hint = (const float*)d_in[1];     // [B,N,M,H]
  const float* node_fts = (const float*)d_in[2]; // [B,N,M,H]
  const float* edge_fts = (const float*)d_in[3]; // [B,E,H]
  const float* edge_W = (const float*)d_in[4];   // [H,1]
  const float* edge_b = (const float*)d_in[5];   // [1]
  const float* update_W = (const float*)d_in[6]; // [H,H]
  const float* update_b = (const float*)d_in[7]; // [H]
  float* out = (float*)d_out;

  char* ws = (char*)d_ws;
  int* cnt = (int*)ws;                                   // B*N ints   (32 KB)
  int2* packed = (int2*)(ws + (size_t)BB * NN * 4);      // B*N*CAP int2 (2 MB)

  // 1) zero counters
  k_zero<<<(BB * NN + 255) / 256, 256, 0, stream>>>(cnt, BB * NN);
  // 2) per-edge coefficient + build packed (src,coeff) lists
  k_coeff_build<<<(BB * EE) / 4, 256, 0, stream>>>(edge_fts, edge_W, edge_b, cfg, cnt, packed);
  // 3) fused gather-max + linear update
  k_fused<<<(BB * NN) / NPB, 256, 0, stream>>>(hint, node_fts, cnt, packed,
                                               update_W, update_b, out);
}

// Round 6
// 162.289 us; speedup vs baseline: 1.0101x; 1.0101x over previous
//
#include <hip/hip_runtime.h>

// Problem constants (fixed by the reference setup)
#define BB 2
#define NN 4096
#define EE 65536
#define MM 4
#define HH 256
#define CAP 32   // actual in-degree is exactly 16 per node; 32 gives safety margin
#define NPB 8    // nodes per block in the fused kernel

typedef float vf4 __attribute__((ext_vector_type(4)));
typedef int vi2 __attribute__((ext_vector_type(2)));

// ---------------------------------------------------------------------------
// Kernel 1: zero the per-node counters
// ---------------------------------------------------------------------------
__global__ void k_zero(int* __restrict__ p, int n) {
  const int i = blockIdx.x * blockDim.x + threadIdx.x;
  if (i < n) p[i] = 0;
}

// ---------------------------------------------------------------------------
// Kernel 2 (fused coeff+build): one 64-lane wave per edge.
//   coeff = edge_fts[b,e,:] . edge_W + edge_b   (float4/lane + shuffle reduce)
//   lane 0: slot = (b, tgt); p = atomicAdd(cnt); packed[slot*CAP+p] = {src, coeff}
// ---------------------------------------------------------------------------
__global__ __launch_bounds__(256) void k_coeff_build(const float* __restrict__ edge_fts,
                                                     const float* __restrict__ edge_W,
                                                     const float* __restrict__ edge_b,
                                                     const int* __restrict__ cfg,
                                                     int* __restrict__ cnt,
                                                     int2* __restrict__ packed) {
  const int gid = blockIdx.x * blockDim.x + threadIdx.x;
  const int widx = gid >> 6;   // flat edge index b*E+e
  const int lane = gid & 63;
  if (widx >= BB * EE) return;
  const vf4 ef = __builtin_nontemporal_load(
      reinterpret_cast<const vf4*>(edge_fts + (size_t)widx * HH + lane * 4));
  const float4 wv = *reinterpret_cast<const float4*>(edge_W + lane * 4);
  float s = ef.x * wv.x + ef.y * wv.y + ef.z * wv.z + ef.w * wv.w;
#pragma unroll
  for (int off = 32; off > 0; off >>= 1) s += __shfl_down(s, off);
  if (lane == 0) {
    const int b = widx >> 16;  // E = 65536
    const vi2 st = __builtin_nontemporal_load(
        reinterpret_cast<const vi2*>(cfg + (size_t)widx * 2));  // (src, tgt)
    const int slot = b * NN + st.y;
    const int p = atomicAdd(&cnt[slot], 1);
    if (p < CAP) {
      int2 v;
      v.x = st.x;                              // src node
      v.y = __float_as_int(s + edge_b[0]);     // coeff
      packed[(size_t)slot * CAP + p] = v;
    }
  }
}

__device__ __forceinline__ float4 fmax4(const float4& a, const float4& b) {
  return make_float4(fmaxf(a.x, b.x), fmaxf(a.y, b.y), fmaxf(a.z, b.z), fmaxf(a.w, b.w));
}

// ---------------------------------------------------------------------------
// Kernel 3 (fused): per block of 8 nodes:
//   stage 0: stage the block's 8x16 (src,coeff) pairs into LDS
//   stage 1: x[i,m,h] = node_fts + max_e coeff[e]*hint[src[e],m,h]  -> LDS (32KB)
//            (deg==16 fast path: 16 INDEPENDENT float4 loads in flight, fmax tree)
//   stage 2: out = x @ W + bias  (fp32 VALU GEMM, 32x256 @ 256x256)
//            W staged through LDS in 16-row (16KB) tiles, loaded ONCE per block
//            -> W L1 traffic 1MB/block -> 256KB/block (was the L1-BW limiter).
//            xs reads wave-uniform (broadcast); wt reads dense 1KB/wave.
//            thread t -> rows (t>>6)*8..+7, cols j0=(t&63)*4..+3
// ---------------------------------------------------------------------------
__global__ __launch_bounds__(256) void k_fused(const float* __restrict__ hint,
                                               const float* __restrict__ node_fts,
                                               const int* __restrict__ cnt,
                                               const int2* __restrict__ packed,
                                               const float* __restrict__ W,
                                               const float* __restrict__ bias,
                                               float* __restrict__ out) {
  __shared__ float xs[NPB * MM][HH];  // 32 KB
  __shared__ float wt[16][HH];        // 16 KB W tile
  __shared__ int ssrc[NPB][16];
  __shared__ float scf[NPB][16];
  __shared__ int sdeg[NPB];

  const int t = threadIdx.x;
  const int blk = blockIdx.x;
  const int b = blk / (NN / NPB);
  const int n0 = (blk % (NN / NPB)) * NPB;
  const int m = t >> 6;   // 0..3 (wave id)
  const int hq = t & 63;  // float4 index along H

  const float NEG_INF = __int_as_float(0xff800000);

  // ---- stage 0: stage (src,coeff) pairs ----
  if (t < NPB) sdeg[t] = cnt[b * NN + n0 + t];
  __syncthreads();
  if (t < NPB * 16) {
    const int i = t >> 4, k = t & 15;
    if (k < min(sdeg[i], CAP)) {
      const int2 v = packed[(size_t)(b * NN + n0 + i) * CAP + k];
      ssrc[i][k] = v.x;
      scf[i][k] = __int_as_float(v.y);
    }
  }
  __syncthreads();

  // per-thread base into hint for (b, m, hq)
  const float* hb = hint + (size_t)b * NN * MM * HH + m * HH + hq * 4;

  // ---- stage 1: gather + coeff-scale + max + add node_fts ----
#pragma unroll 1
  for (int i = 0; i < NPB; ++i) {
    const int deg = sdeg[i];
    float4 acc;
    if (deg == 16) {
      float4 hv[16];
#pragma unroll
      for (int k = 0; k < 16; ++k) {
        const int s = ssrc[i][k];
        hv[k] = *reinterpret_cast<const float4*>(hb + (size_t)s * (MM * HH));
      }
#pragma unroll
      for (int k = 0; k < 16; ++k) {
        const float c = scf[i][k];
        hv[k].x *= c; hv[k].y *= c; hv[k].z *= c; hv[k].w *= c;
      }
#pragma unroll
      for (int off = 8; off > 0; off >>= 1)
#pragma unroll
        for (int k = 0; k < 8; ++k)
          if (k < off) hv[k] = fmax4(hv[k], hv[k + off]);
      acc = hv[0];
    } else {
      // generic path (deg != 16): read packed list straight from global
      acc = make_float4(NEG_INF, NEG_INF, NEG_INF, NEG_INF);
      const int2* pl = packed + (size_t)(b * NN + n0 + i) * CAP;
      const int d = min(deg, CAP);
      for (int k = 0; k < d; ++k) {
        const int2 v = pl[k];
        const float c = __int_as_float(v.y);
        const float4 hv = *reinterpret_cast<const float4*>(hb + (size_t)v.x * (MM * HH));
        acc.x = fmaxf(acc.x, c * hv.x);
        acc.y = fmaxf(acc.y, c * hv.y);
        acc.z = fmaxf(acc.z, c * hv.z);
        acc.w = fmaxf(acc.w, c * hv.w);
      }
    }
    const float4 nf = *reinterpret_cast<const float4*>(
        node_fts + (((size_t)(b * NN + n0 + i) * MM + m) * HH) + hq * 4);
    float4 xv;
    xv.x = nf.x + acc.x;
    xv.y = nf.y + acc.y;
    xv.z = nf.z + acc.z;
    xv.w = nf.w + acc.w;
    *reinterpret_cast<float4*>(&xs[i * MM + m][hq * 4]) = xv;
  }

  // ---- stage 2: [32 x 256] @ [256 x 256] fp32 GEMM, W tiled via LDS ----
  const int j0 = (t & 63) * 4;  // 4 consecutive output columns
  const int rg = t >> 6;        // rows rg*8 .. rg*8+7 (uniform per wave)

  float4 acc2[8];
#pragma unroll
  for (int r = 0; r < 8; ++r) acc2[r] = make_float4(0.f, 0.f, 0.f, 0.f);

  float* wtf = &wt[0][0];
#pragma unroll 1
  for (int tile = 0; tile < 16; ++tile) {
    __syncthreads();  // first iter: also covers stage-1 xs writes
    // cooperative load of 16 W rows (16 KB): thread t copies 4 float4, coalesced
#pragma unroll
    for (int k = 0; k < 4; ++k) {
      const int idx = k * 1024 + t * 4;  // float index within the tile
      *reinterpret_cast<float4*>(wtf + idx) =
          *reinterpret_cast<const float4*>(W + tile * (16 * HH) + idx);
    }
    __syncthreads();
#pragma unroll
    for (int hq2 = 0; hq2 < 4; ++hq2) {
      float4 xv[8];
#pragma unroll
      for (int r = 0; r < 8; ++r)
        xv[r] = *reinterpret_cast<const float4*>(&xs[rg * 8 + r][tile * 16 + hq2 * 4]);
#pragma unroll
      for (int hh = 0; hh < 4; ++hh) {
        const float4 wq = *reinterpret_cast<const float4*>(&wt[hq2 * 4 + hh][j0]);
#pragma unroll
        for (int r = 0; r < 8; ++r) {
          const float xr = (hh == 0) ? xv[r].x : (hh == 1) ? xv[r].y : (hh == 2) ? xv[r].z : xv[r].w;
          acc2[r].x = fmaf(xr, wq.x, acc2[r].x);
          acc2[r].y = fmaf(xr, wq.y, acc2[r].y);
          acc2[r].z = fmaf(xr, wq.z, acc2[r].z);
          acc2[r].w = fmaf(xr, wq.w, acc2[r].w);
        }
      }
    }
  }

  // ---- write out (+bias), nontemporal float4 per row ----
  const float4 bq = *reinterpret_cast<const float4*>(bias + j0);
#pragma unroll
  for (int r = 0; r < 8; ++r) {
    const int row = rg * 8 + r;
    const int i = row >> 2;
    const int m2 = row & 3;
    vf4 o;
    o.x = acc2[r].x + bq.x;
    o.y = acc2[r].y + bq.y;
    o.z = acc2[r].z + bq.z;
    o.w = acc2[r].w + bq.w;
    __builtin_nontemporal_store(
        o, reinterpret_cast<vf4*>(out + (((size_t)(b * NN + n0 + i) * MM + m2) * HH) + j0));
  }
}

// ---------------------------------------------------------------------------
extern "C" void kernel_launch(void* const* d_in, const int* in_sizes, int n_in,
                              void* d_out, int out_size, void* d_ws, size_t ws_size,
                              hipStream_t stream) {
  const int* cfg = (const int*)d_in[0];          // [B,E,2]
  const float* hint = (const float*)d_in[1];     // [B,N,M,H]
  const float* node_fts = (const float*)d_in[2]; // [B,N,M,H]
  const float* edge_fts = (const float*)d_in[3]; // [B,E,H]
  const float* edge_W = (const float*)d_in[4];   // [H,1]
  const float* edge_b = (const float*)d_in[5];   // [1]
  const float* update_W = (const float*)d_in[6]; // [H,H]
  const float* update_b = (const float*)d_in[7]; // [H]
  float* out = (float*)d_out;

  char* ws = (char*)d_ws;
  int* cnt = (int*)ws;                                   // B*N ints   (32 KB)
  int2* packed = (int2*)(ws + (size_t)BB * NN * 4);      // B*N*CAP int2 (2 MB)

  // 1) zero counters
  k_zero<<<(BB * NN + 255) / 256, 256, 0, stream>>>(cnt, BB * NN);
  // 2) per-edge coefficient + build packed (src,coeff) lists
  k_coeff_build<<<(BB * EE) / 4, 256, 0, stream>>>(edge_fts, edge_W, edge_b, cfg, cnt, packed);
  // 3) fused gather-max + linear update (W staged via LDS)
  k_fused<<<(BB * NN) / NPB, 256, 0, stream>>>(hint, node_fts, cnt, packed,
                                               update_W, update_b, out);
}

// Round 7
// 136.450 us; speedup vs baseline: 1.2013x; 1.1894x over previous
//
#include <hip/hip_runtime.h>

// Problem constants (fixed by the reference setup)
#define BB 2
#define NN 4096
#define EE 65536
#define MM 4
#define HH 256
#define CAP 32     // actual in-degree is exactly 16 per node
#define NPB 32     // nodes per block (one m-slice each) in the fused kernel
#define NXCD 8

typedef float vf4 __attribute__((ext_vector_type(4)));
typedef int vi2 __attribute__((ext_vector_type(2)));

// ---------------------------------------------------------------------------
// Kernel 1: zero the per-node counters
// ---------------------------------------------------------------------------
__global__ void k_zero(int* __restrict__ p, int n) {
  const int i = blockIdx.x * blockDim.x + threadIdx.x;
  if (i < n) p[i] = 0;
}

// ---------------------------------------------------------------------------
// Kernel 2 (fused coeff+build): one 64-lane wave per edge.
//   coeff = edge_fts[b,e,:] . edge_W + edge_b   (float4/lane + shuffle reduce)
//   lane 0: slot = (b, tgt); p = atomicAdd(cnt); packed[slot*CAP+p] = {src, coeff}
// ---------------------------------------------------------------------------
__global__ __launch_bounds__(256) void k_coeff_build(const float* __restrict__ edge_fts,
                                                     const float* __restrict__ edge_W,
                                                     const float* __restrict__ edge_b,
                                                     const int* __restrict__ cfg,
                                                     int* __restrict__ cnt,
                                                     int2* __restrict__ packed) {
  const int gid = blockIdx.x * blockDim.x + threadIdx.x;
  const int widx = gid >> 6;   // flat edge index b*E+e
  const int lane = gid & 63;
  if (widx >= BB * EE) return;
  const vf4 ef = __builtin_nontemporal_load(
      reinterpret_cast<const vf4*>(edge_fts + (size_t)widx * HH + lane * 4));
  const float4 wv = *reinterpret_cast<const float4*>(edge_W + lane * 4);
  float s = ef.x * wv.x + ef.y * wv.y + ef.z * wv.z + ef.w * wv.w;
#pragma unroll
  for (int off = 32; off > 0; off >>= 1) s += __shfl_down(s, off);
  if (lane == 0) {
    const int b = widx >> 16;  // E = 65536
    const vi2 st = __builtin_nontemporal_load(
        reinterpret_cast<const vi2*>(cfg + (size_t)widx * 2));  // (src, tgt)
    const int slot = b * NN + st.y;
    const int p = atomicAdd(&cnt[slot], 1);
    if (p < CAP) {
      int2 v;
      v.x = st.x;                              // src node
      v.y = __float_as_int(s + edge_b[0]);     // coeff
      packed[(size_t)slot * CAP + p] = v;
    }
  }
}

__device__ __forceinline__ float4 fmax4(const float4& a, const float4& b) {
  return make_float4(fmaxf(a.x, b.x), fmaxf(a.y, b.y), fmaxf(a.z, b.z), fmaxf(a.w, b.w));
}

// ---------------------------------------------------------------------------
// Kernel 3 (fused, XCD-sharded): block = (unit, chunk), unit = blockIdx%8 =
// b*4+m. Under round-robin block->XCD dispatch, XCD u only touches hint slice
// (b,m)=u: 4096 rows x 1KB = 4.2 MB -> L2-RESIDENT; all 16x gather reuse stays
// in one XCD's L2 (kills the ~7x cross-XCD fill replication seen as 224MB FETCH).
//   stage 0: stage 32 nodes' (src,coeff) pairs into LDS (pad-replicate to 16)
//   stage 1: wave w, node i: 16 independent 1KB-row loads, scale, fmax tree,
//            + node_fts -> xs[32][256] (32 KB)
//   stage 2: out[n,m,:] = xs @ W + bias; thread t -> rows (t>>6)*8..+7,
//            cols (t&63)*4..+3; W rows from global (L1/L2), xs via LDS broadcast
// ---------------------------------------------------------------------------
__global__ __launch_bounds__(256) void k_fused(const float* __restrict__ hint,
                                               const float* __restrict__ node_fts,
                                               const int* __restrict__ cnt,
                                               const int2* __restrict__ packed,
                                               const float* __restrict__ W,
                                               const float* __restrict__ bias,
                                               float* __restrict__ out) {
  __shared__ float xs[NPB][HH];    // 32 KB
  __shared__ int ssrc[NPB][16];    // 2 KB
  __shared__ float scf[NPB][16];   // 2 KB
  __shared__ int sdeg[NPB];

  const int t = threadIdx.x;
  const int unit = blockIdx.x & (NXCD - 1);   // = b*4 + m  (XCD-pinned slice)
  const int chunk = blockIdx.x >> 3;          // node chunk
  const int b = unit >> 2;
  const int m = unit & 3;
  const int n0 = chunk * NPB;
  const int wave = t >> 6;  // 0..3
  const int lane = t & 63;

  // ---- stage 0: stage (src,coeff) pairs, clamped-index pad to 16 ----
  if (t < NPB) sdeg[t] = min(cnt[b * NN + n0 + t], CAP);
  __syncthreads();
#pragma unroll
  for (int s = t; s < NPB * 16; s += 256) {
    const int i = s >> 4, k = s & 15;
    const int d = sdeg[i];
    // deg is 16 by construction; clamp handles deg<16 by replicating edge 0
    const int kk = (k < d) ? k : (d > 0 ? 0 : 0);
    const int2 v = packed[(size_t)(b * NN + n0 + i) * CAP + kk];
    ssrc[i][k] = v.x;
    scf[i][k] = __int_as_float(v.y);
  }
  __syncthreads();

  // per-thread base into hint for (b, m, lane)
  const float* hb = hint + (size_t)b * NN * MM * HH + m * HH + lane * 4;

  // ---- stage 1: gather + coeff-scale + max + add node_fts ----
#pragma unroll 1
  for (int i = 0; i < 8; ++i) {
    const int lr = wave * 8 + i;     // local row 0..31
    const int n = n0 + lr;
    float4 hv[16];
#pragma unroll
    for (int k = 0; k < 16; ++k) {
      const int s = ssrc[lr][k];
      hv[k] = *reinterpret_cast<const float4*>(hb + (size_t)s * (MM * HH));
    }
#pragma unroll
    for (int k = 0; k < 16; ++k) {
      const float c = scf[lr][k];
      hv[k].x *= c; hv[k].y *= c; hv[k].z *= c; hv[k].w *= c;
    }
#pragma unroll
    for (int off = 8; off > 0; off >>= 1)
#pragma unroll
      for (int k = 0; k < 8; ++k)
        if (k < off) hv[k] = fmax4(hv[k], hv[k + off]);
    const float4 nf = *reinterpret_cast<const float4*>(
        node_fts + (((size_t)(b * NN + n) * MM + m) * HH) + lane * 4);
    float4 xv;
    xv.x = nf.x + hv[0].x;
    xv.y = nf.y + hv[0].y;
    xv.z = nf.z + hv[0].z;
    xv.w = nf.w + hv[0].w;
    *reinterpret_cast<float4*>(&xs[lr][lane * 4]) = xv;
  }
  __syncthreads();

  // ---- stage 2: [32 x 256] @ [256 x 256] fp32 GEMM ----
  const int j0 = (t & 63) * 4;  // 4 consecutive output columns
  const int rg = t >> 6;        // rows rg*8 .. rg*8+7 (uniform per wave)

  float4 acc2[8];
#pragma unroll
  for (int r = 0; r < 8; ++r) acc2[r] = make_float4(0.f, 0.f, 0.f, 0.f);

  for (int hq2 = 0; hq2 < HH / 4; ++hq2) {
    float4 xv[8];
#pragma unroll
    for (int r = 0; r < 8; ++r)
      xv[r] = *reinterpret_cast<const float4*>(&xs[rg * 8 + r][hq2 * 4]);
#pragma unroll
    for (int hh = 0; hh < 4; ++hh) {
      const float4 wq = *reinterpret_cast<const float4*>(W + (size_t)(hq2 * 4 + hh) * HH + j0);
#pragma unroll
      for (int r = 0; r < 8; ++r) {
        const float xr = (hh == 0) ? xv[r].x : (hh == 1) ? xv[r].y : (hh == 2) ? xv[r].z : xv[r].w;
        acc2[r].x = fmaf(xr, wq.x, acc2[r].x);
        acc2[r].y = fmaf(xr, wq.y, acc2[r].y);
        acc2[r].z = fmaf(xr, wq.z, acc2[r].z);
        acc2[r].w = fmaf(xr, wq.w, acc2[r].w);
      }
    }
  }

  // ---- write out (+bias), nontemporal float4 per row ----
  const float4 bq = *reinterpret_cast<const float4*>(bias + j0);
#pragma unroll
  for (int r = 0; r < 8; ++r) {
    const int n = n0 + rg * 8 + r;
    vf4 o;
    o.x = acc2[r].x + bq.x;
    o.y = acc2[r].y + bq.y;
    o.z = acc2[r].z + bq.z;
    o.w = acc2[r].w + bq.w;
    __builtin_nontemporal_store(
        o, reinterpret_cast<vf4*>(out + (((size_t)(b * NN + n) * MM + m) * HH) + j0));
  }
}

// ---------------------------------------------------------------------------
extern "C" void kernel_launch(void* const* d_in, const int* in_sizes, int n_in,
                              void* d_out, int out_size, void* d_ws, size_t ws_size,
                              hipStream_t stream) {
  const int* cfg = (const int*)d_in[0];          // [B,E,2]
  const float* hint = (const float*)d_in[1];     // [B,N,M,H]
  const float* node_fts = (const float*)d_in[2]; // [B,N,M,H]
  const float* edge_fts = (const float*)d_in[3]; // [B,E,H]
  const float* edge_W = (const float*)d_in[4];   // [H,1]
  const float* edge_b = (const float*)d_in[5];   // [1]
  const float* update_W = (const float*)d_in[6]; // [H,H]
  const float* update_b = (const float*)d_in[7]; // [H]
  float* out = (float*)d_out;

  char* ws = (char*)d_ws;
  int* cnt = (int*)ws;                                   // B*N ints   (32 KB)
  int2* packed = (int2*)(ws + (size_t)BB * NN * 4);      // B*N*CAP int2 (2 MB)

  // 1) zero counters
  k_zero<<<(BB * NN + 255) / 256, 256, 0, stream>>>(cnt, BB * NN);
  // 2) per-edge coefficient + build packed (src,coeff) lists
  k_coeff_build<<<(BB * EE) / 4, 256, 0, stream>>>(edge_fts, edge_W, edge_b, cfg, cnt, packed);
  // 3) fused gather-max + linear update; grid = (B*M) x (N/NPB), unit-major
  //    (blockIdx%8 = (b,m) unit -> one hint m-slice per XCD under round-robin)
  k_fused<<<BB * MM * (NN / NPB), 256, 0, stream>>>(hint, node_fts, cnt, packed,
                                                    update_W, update_b, out);
}

// Round 9
// 133.947 us; speedup vs baseline: 1.2238x; 1.0187x over previous
//
#include <hip/hip_runtime.h>

// Problem constants (fixed by the reference setup)
#define BB 2
#define NN 4096
#define EE 65536
#define MM 4
#define HH 256
#define CAP 32     // in-degree is exactly 16 per node by construction
#define NPB 32     // nodes per block (one m-slice each) in the fused kernel
#define NXCD 8

typedef float vf4 __attribute__((ext_vector_type(4)));
typedef int vi2 __attribute__((ext_vector_type(2)));

// ---------------------------------------------------------------------------
// Kernel 1: zero the per-node counters
// ---------------------------------------------------------------------------
__global__ void k_zero(int* __restrict__ p, int n) {
  const int i = blockIdx.x * blockDim.x + threadIdx.x;
  if (i < n) p[i] = 0;
}

// ---------------------------------------------------------------------------
// Kernel 2 (fused coeff+build): one 64-lane wave per edge.
//   coeff = edge_fts[b,e,:] . edge_W + edge_b   (float4/lane + shuffle reduce)
//   lane 0: slot = (b, tgt); p = atomicAdd(cnt); packed[slot*CAP+p] = {src, coeff}
// ---------------------------------------------------------------------------
__global__ __launch_bounds__(256) void k_coeff_build(const float* __restrict__ edge_fts,
                                                     const float* __restrict__ edge_W,
                                                     const float* __restrict__ edge_b,
                                                     const int* __restrict__ cfg,
                                                     int* __restrict__ cnt,
                                                     int2* __restrict__ packed) {
  const int gid = blockIdx.x * blockDim.x + threadIdx.x;
  const int widx = gid >> 6;   // flat edge index b*E+e
  const int lane = gid & 63;
  if (widx >= BB * EE) return;
  const vf4 ef = __builtin_nontemporal_load(
      reinterpret_cast<const vf4*>(edge_fts + (size_t)widx * HH + lane * 4));
  const float4 wv = *reinterpret_cast<const float4*>(edge_W + lane * 4);
  float s = ef.x * wv.x + ef.y * wv.y + ef.z * wv.z + ef.w * wv.w;
#pragma unroll
  for (int off = 32; off > 0; off >>= 1) s += __shfl_down(s, off);
  if (lane == 0) {
    const int b = widx >> 16;  // E = 65536
    const vi2 st = __builtin_nontemporal_load(
        reinterpret_cast<const vi2*>(cfg + (size_t)widx * 2));  // (src, tgt)
    const int slot = b * NN + st.y;
    const int p = atomicAdd(&cnt[slot], 1);
    if (p < CAP) {
      int2 v;
      v.x = st.x;                              // src node
      v.y = __float_as_int(s + edge_b[0]);     // coeff
      packed[(size_t)slot * CAP + p] = v;
    }
  }
}

__device__ __forceinline__ float4 fmax4(const float4& a, const float4& b) {
  return make_float4(fmaxf(a.x, b.x), fmaxf(a.y, b.y), fmaxf(a.z, b.z), fmaxf(a.w, b.w));
}

// ---------------------------------------------------------------------------
// Kernel 3 (fused, XCD-sharded, BARRIER-FREE): block = (unit, chunk),
// unit = blockIdx%8 = b*4+m -> each XCD touches only its 4.2MB hint slice
// (L2-resident; verified r7: FETCH 224->67MB).
// NEW: zero __syncthreads. All dataflow is intra-wave: wave w stages, gathers,
// and GEMMs rows w*8..w*8+7 only. Waves drift out of phase so one wave's GEMM
// VALU hides another's L2 gather latency on the same SIMD (r7 was phase-locked:
// whole grid gathered simultaneously, then GEMM'd simultaneously -> 62% idle).
//   per-wave stage 0: 8 rows x 16 (src,coeff) -> LDS (2 int2 per lane)
//   stage 1: per row: 16 independent 1KB-row loads, scale, fmax tree, +node_fts
//            -> xs[row][lane*4..+3]
//   stage 2: out rows r0..r0+7 = xs @ W + bias; lane -> cols lane*4..+3
// ---------------------------------------------------------------------------
__global__ __launch_bounds__(256) void k_fused(const float* __restrict__ hint,
                                               const float* __restrict__ node_fts,
                                               const int* __restrict__ cnt,
                                               const int2* __restrict__ packed,
                                               const float* __restrict__ W,
                                               const float* __restrict__ bias,
                                               float* __restrict__ out) {
  __shared__ float xs[NPB][HH];    // 32 KB
  __shared__ int ssrc[NPB][16];    // 2 KB
  __shared__ float scf[NPB][16];   // 2 KB

  const int t = threadIdx.x;
  const int unit = blockIdx.x & (NXCD - 1);   // = b*4 + m  (XCD-pinned slice)
  const int chunk = blockIdx.x >> 3;          // node chunk
  const int b = unit >> 2;
  const int m = unit & 3;
  const int n0 = chunk * NPB;
  const int w = t >> 6;     // wave 0..3
  const int lane = t & 63;
  const int r0 = w * 8;     // this wave's first local row

  // ---- per-wave stage 0: stage this wave's 8 rows' (src,coeff) pairs ----
  // in-degree is exactly 16 by construction; clamp k for safety (dup edges are
  // no-ops under max).
#pragma unroll
  for (int q = 0; q < 2; ++q) {
    const int idx = q * 64 + lane;      // 0..127
    const int i = idx >> 4, k = idx & 15;
    const int node = b * NN + n0 + r0 + i;
    const int d = cnt[node];
    const int kk = (k < d) ? k : 0;
    const int2 v = packed[(size_t)node * CAP + kk];
    ssrc[r0 + i][k] = v.x;
    scf[r0 + i][k] = __int_as_float(v.y);
  }

  // per-thread base into hint for (b, m, lane)
  const float* hb = hint + (size_t)b * NN * MM * HH + m * HH + lane * 4;

  // ---- stage 1: gather + coeff-scale + max + add node_fts (own rows) ----
#pragma unroll 1
  for (int i = 0; i < 8; ++i) {
    const int lr = r0 + i;           // local row
    const int n = n0 + lr;           // node
    float4 hv[16];
#pragma unroll
    for (int k = 0; k < 16; ++k) {
      const int s = ssrc[lr][k];
      hv[k] = *reinterpret_cast<const float4*>(hb + (size_t)s * (MM * HH));
    }
#pragma unroll
    for (int k = 0; k < 16; ++k) {
      const float c = scf[lr][k];
      hv[k].x *= c; hv[k].y *= c; hv[k].z *= c; hv[k].w *= c;
    }
#pragma unroll
    for (int off = 8; off > 0; off >>= 1)
#pragma unroll
      for (int k = 0; k < 8; ++k)
        if (k < off) hv[k] = fmax4(hv[k], hv[k + off]);
    const float4 nf = *reinterpret_cast<const float4*>(
        node_fts + (((size_t)(b * NN + n) * MM + m) * HH) + lane * 4);
    float4 xv;
    xv.x = nf.x + hv[0].x;
    xv.y = nf.y + hv[0].y;
    xv.z = nf.z + hv[0].z;
    xv.w = nf.w + hv[0].w;
    *reinterpret_cast<float4*>(&xs[lr][lane * 4]) = xv;
  }
  // no barrier: stage 2 reads only this wave's xs rows (lgkmcnt ordering)

  // ---- stage 2: [8 x 256] @ [256 x 256] fp32 GEMM (own rows) ----
  const int j0 = lane * 4;  // 4 consecutive output columns

  float4 acc2[8];
#pragma unroll
  for (int r = 0; r < 8; ++r) acc2[r] = make_float4(0.f, 0.f, 0.f, 0.f);

  for (int hq2 = 0; hq2 < HH / 4; ++hq2) {
    float4 xv[8];
#pragma unroll
    for (int r = 0; r < 8; ++r)
      xv[r] = *reinterpret_cast<const float4*>(&xs[r0 + r][hq2 * 4]);
#pragma unroll
    for (int hh = 0; hh < 4; ++hh) {
      const float4 wq = *reinterpret_cast<const float4*>(W + (size_t)(hq2 * 4 + hh) * HH + j0);
#pragma unroll
      for (int r = 0; r < 8; ++r) {
        const float xr = (hh == 0) ? xv[r].x : (hh == 1) ? xv[r].y : (hh == 2) ? xv[r].z : xv[r].w;
        acc2[r].x = fmaf(xr, wq.x, acc2[r].x);
        acc2[r].y = fmaf(xr, wq.y, acc2[r].y);
        acc2[r].z = fmaf(xr, wq.z, acc2[r].z);
        acc2[r].w = fmaf(xr, wq.w, acc2[r].w);
      }
    }
  }

  // ---- write out (+bias), nontemporal float4 per row ----
  const float4 bq = *reinterpret_cast<const float4*>(bias + j0);
#pragma unroll
  for (int r = 0; r < 8; ++r) {
    const int n = n0 + r0 + r;
    vf4 o;
    o.x = acc2[r].x + bq.x;
    o.y = acc2[r].y + bq.y;
    o.z = acc2[r].z + bq.z;
    o.w = acc2[r].w + bq.w;
    __builtin_nontemporal_store(
        o, reinterpret_cast<vf4*>(out + (((size_t)(b * NN + n) * MM + m) * HH) + j0));
  }
}

// ---------------------------------------------------------------------------
extern "C" void kernel_launch(void* const* d_in, const int* in_sizes, int n_in,
                              void* d_out, int out_size, void* d_ws, size_t ws_size,
                              hipStream_t stream) {
  const int* cfg = (const int*)d_in[0];          // [B,E,2]
  const float* hint = (const float*)d_in[1];     // [B,N,M,H]
  const float* node_fts = (const float*)d_in[2]; // [B,N,M,H]
  const float* edge_fts = (const float*)d_in[3]; // [B,E,H]
  const float* edge_W = (const float*)d_in[4];   // [H,1]
  const float* edge_b = (const float*)d_in[5];   // [1]
  const float* update_W = (const float*)d_in[6]; // [H,H]
  const float* update_b = (const float*)d_in[7]; // [H]
  float* out = (float*)d_out;

  char* ws = (char*)d_ws;
  int* cnt = (int*)ws;                                   // B*N ints   (32 KB)
  int2* packed = (int2*)(ws + (size_t)BB * NN * 4);      // B*N*CAP int2 (2 MB)

  // 1) zero counters
  k_zero<<<(BB * NN + 255) / 256, 256, 0, stream>>>(cnt, BB * NN);
  // 2) per-edge coefficient + build packed (src,coeff) lists
  k_coeff_build<<<(BB * EE) / 4, 256, 0, stream>>>(edge_fts, edge_W, edge_b, cfg, cnt, packed);
  // 3) fused gather-max + linear update; grid = (B*M) x (N/NPB), unit-major
  //    (blockIdx%8 = (b,m) unit -> one hint m-slice per XCD under round-robin)
  k_fused<<<BB * MM * (NN / NPB), 256, 0, stream>>>(hint, node_fts, cnt, packed,
                                                    update_W, update_b, out);
}